// Round 1
// baseline (3616.588 us; speedup 1.0000x reference)
//
#include <hip/hip_runtime.h>
#include <stdint.h>
#include <stddef.h>

#define BATCH 4096
#define HID   1024
#define EMB   64
#define NKH   32      // h K-tiles of 32
#define NSTEP 19
#define NOBS  8
#define WSL   139264  // halfs per 128-pcol slice of Wsw: 34*8*512

typedef _Float16 f16;
typedef _Float16 half8 __attribute__((ext_vector_type(8)));
typedef float    float4v __attribute__((ext_vector_type(4)));

__device__ __forceinline__ float sigm(float x) { return 1.f / (1.f + __expf(-x)); }
__device__ __forceinline__ float tanh_f(float x) { return 1.f - 2.f / (__expf(2.f * x) + 1.f); }

typedef const __attribute__((address_space(1))) unsigned int gau32;
typedef __attribute__((address_space(3))) unsigned int lau32;

__device__ __forceinline__ void gload16(const void* src, void* lds) {
  // global->LDS direct copy, 16 B/lane; LDS dest is wave-uniform base + lane*16
  __builtin_amdgcn_global_load_lds((gau32*)src, (lau32*)lds, 16, 0, 0);
}

// ---------------------------------------------------------------------------
// Pack W_ih|W_hh -> fragment-major fp16 Wsw[slice][kt][ni][lane][8].
// NEW pcol mapping (gates within a wave's 4 ni tiles):
//   p = bn*256 + wn*64 + g*16 + v ; unit u = bn*64 + wn*16 + v ; orig = g*HID+u
//   i.e. g = (p>>4)&3, u = (p>>8)*64 + ((p>>6)&3)*16 + (p&15)
// k = kt*32 + (lane>>4)*8 + e ; kt 0,1 = emb (W_ih), kt 2..33 = h (W_hh).
// ---------------------------------------------------------------------------
__global__ void pack_kernel(const float* __restrict__ W_ih, const float* __restrict__ b_ih,
                            const float* __restrict__ W_hh, const float* __restrict__ b_hh,
                            f16* __restrict__ Wsw, float* __restrict__ bc) {
  int gid = blockIdx.x * blockDim.x + threadIdx.x;  // 32 * WSL
  int tt = gid / WSL;
  int rem = gid - tt * WSL;
  int kt = rem >> 12;
  int ni = (rem >> 9) & 7;
  int lane = (rem >> 3) & 63;
  int e = rem & 7;
  int p = tt * 128 + ni * 16 + (lane & 15);
  int g = (p >> 4) & 3;
  int u = (p >> 8) * 64 + ((p >> 6) & 3) * 16 + (p & 15);
  int orig = g * HID + u;
  int k = kt * 32 + ((lane >> 4) << 3) + e;
  float val = (k < EMB) ? W_ih[orig * EMB + k] : W_hh[orig * HID + (k - EMB)];
  Wsw[gid] = (f16)val;
  if (k == 0) bc[p] = b_ih[orig] + b_hh[orig];
}

// out[t][row][o] accumulated via atomics -> pre-init to b_out.
__global__ __launch_bounds__(1024)
void init_out_kernel(const float* __restrict__ b_out, float* __restrict__ out) {
  int i = blockIdx.x * 1024 + threadIdx.x;  // grid exactly covers 19*4096*5
  out[i] = b_out[i % 5];
}

// ---------------------------------------------------------------------------
// 256x256-tile fused gates-GEMM + LSTM cell + out-proj (atomics).
// 8 waves (2M x 4N), BK=64, LDS double-buffered via global_load_lds,
// one __syncthreads per K-step, staging issued a full K-step ahead.
// Wave (wm,wn): rows wm*128 (8 rowtiles), cols wn*64 = 4 ni tiles = 4 gates
// of units bn*64 + wn*16 + l15.
// LDS map (halfs): buf p at p*32768:
//   A chunk (rtl 0..15, khl 0..1): (rtl*2+khl)*512
//   B chunk (sh, nisl 0..7, khl):  16384 + ((sh*8+nisl)*2+khl)*512
// ---------------------------------------------------------------------------
__global__ __launch_bounds__(512, 2)
void gemm_cell_kernel(const f16* __restrict__ Xp, const f16* __restrict__ Wsw,
                      const float* __restrict__ bc,
                      f16* __restrict__ c_ws, f16* __restrict__ Xn,
                      float* __restrict__ out_t, const float* __restrict__ W_out,
                      const float* __restrict__ obs_t, const float* __restrict__ outprev,
                      int mode, const float* __restrict__ W_emb,
                      const float* __restrict__ b_emb) {
  __shared__ f16 smem[65536];  // 128 KiB

  const int tid = threadIdx.x;
  const int lane = tid & 63;
  const int w = tid >> 6;
  const int l15 = lane & 15;
  const int quad = lane >> 4;
  const int wm = w >> 2, wn = w & 3;
  const int sh = wn >> 1, nq = wn & 1;

  // XCD swizzle: XCD x gets bn pair {2x,2x+1} (its B slices stay L2-resident)
  const int id = blockIdx.x;
  const int x = id & 7, rr0 = id >> 3;
  const int bn = x * 2 + (rr0 & 1);
  const int bm = rr0 >> 1;
  const int slice = bn * 2 + sh;  // 128-col slice this wave reads B from

  float4v acc[8][4];
#pragma unroll
  for (int mi = 0; mi < 8; ++mi)
#pragma unroll
    for (int ni = 0; ni < 4; ++ni) acc[mi][ni] = (float4v){0.f, 0.f, 0.f, 0.f};

  // stage K-step sp (1..16) into LDS buf (sp&1); 8 gloads per wave
  auto stage = [&](int sp) {
    const int p2 = sp & 1;
    const int khg = 2 * (sp - 1);
#pragma unroll
    for (int i = 0; i < 4; ++i) {  // A: this wave covers 4 of 32 chunks
      const int c = wn * 4 + i;
      const int rtl = wm * 8 + (c >> 1), khl = c & 1;
      const f16* src = Xp + ((size_t)(bm * 16 + rtl) * NKH + (khg + khl)) * 512 + lane * 8;
      f16* dst = smem + p2 * 32768 + (rtl * 2 + khl) * 512;
      gload16(src, dst);
    }
#pragma unroll
    for (int i = 0; i < 4; ++i) {  // B: 4 of 32 chunks (own slice half)
      const int c = (wm * 2 + nq) * 4 + i;
      const int nisl = c >> 1, khl = c & 1;
      const f16* src = Wsw + (size_t)slice * WSL + (2 + khg + khl) * 4096 + nisl * 512 + lane * 8;
      f16* dst = smem + p2 * 32768 + 16384 + ((sh * 8 + nisl) * 2 + khl) * 512;
      gload16(src, dst);
    }
  };

  if (mode != 0) stage(1);  // prologue staging flies under the emb phase

  // ---- emb phase (K 0..63), A computed in-register, B direct from global ----
  {
    float d0[8], d1[8];
#pragma unroll
    for (int mi = 0; mi < 8; ++mi) {
      const int row = (bm * 16 + wm * 8 + mi) * 16 + l15;
      if (mode <= 1) {
        const float* o = obs_t + (size_t)row * 2;
        d0[mi] = o[BATCH * 2] - o[0];
        d1[mi] = o[BATCH * 2 + 1] - o[1];
      } else {
        d0[mi] = outprev[(size_t)row * 5 + 0];
        d1[mi] = outprev[(size_t)row * 5 + 1];
      }
    }
#pragma unroll
    for (int kt = 0; kt < 2; ++kt) {
      float w0[8], w1[8], be[8];
#pragma unroll
      for (int e = 0; e < 8; ++e) {
        const int j = kt * 32 + quad * 8 + e;
        w0[e] = W_emb[2 * j];
        w1[e] = W_emb[2 * j + 1];
        be[e] = b_emb[j];
      }
      half8 bfe[4];
#pragma unroll
      for (int ni = 0; ni < 4; ++ni)
        bfe[ni] = *(const half8*)(Wsw + (size_t)slice * WSL + kt * 4096 + (nq * 4 + ni) * 512 + lane * 8);
#pragma unroll
      for (int mi = 0; mi < 8; ++mi) {
        half8 ae;
#pragma unroll
        for (int e = 0; e < 8; ++e)
          ae[e] = (f16)fmaxf(d0[mi] * w0[e] + d1[mi] * w1[e] + be[e], 0.f);
#pragma unroll
        for (int ni = 0; ni < 4; ++ni)
          acc[mi][ni] = __builtin_amdgcn_mfma_f32_16x16x32_f16(ae, bfe[ni], acc[mi][ni], 0, 0, 0);
      }
    }
  }

  // ---- h phase: 16 K-steps of 64, LDS double-buffered ----
  if (mode != 0) {
    for (int s = 1; s <= 16; ++s) {
      __syncthreads();            // drains staging for s (issued one K-step ago)
      if (s < 16) stage(s + 1);   // in flight across this whole K-step

      const f16* base = smem + (s & 1) * 32768;
      half8 a[8][2], b8[4][2];
#pragma unroll
      for (int mi = 0; mi < 8; ++mi)
#pragma unroll
        for (int khl = 0; khl < 2; ++khl)
          a[mi][khl] = *(const half8*)(base + ((wm * 8 + mi) * 2 + khl) * 512 + lane * 8);
#pragma unroll
      for (int ni = 0; ni < 4; ++ni)
#pragma unroll
        for (int khl = 0; khl < 2; ++khl)
          b8[ni][khl] = *(const half8*)(base + 16384 + ((sh * 8 + nq * 4 + ni) * 2 + khl) * 512 + lane * 8);

#pragma unroll
      for (int mh = 0; mh < 2; ++mh)
#pragma unroll
        for (int nh = 0; nh < 2; ++nh) {
          __builtin_amdgcn_s_setprio(1);
#pragma unroll
          for (int m2 = 0; m2 < 4; ++m2)
#pragma unroll
            for (int n2 = 0; n2 < 2; ++n2)
#pragma unroll
              for (int khl = 0; khl < 2; ++khl) {
                const int mi = mh * 4 + m2, ni = nh * 2 + n2;
                acc[mi][ni] =
                    __builtin_amdgcn_mfma_f32_16x16x32_f16(a[mi][khl], b8[ni][khl], acc[mi][ni], 0, 0, 0);
              }
          __builtin_amdgcn_s_setprio(0);
        }
    }
  }

  // ---- epilogue: lane-local LSTM cell + h write + out-proj atomics ----
  float bb[4];
#pragma unroll
  for (int ni = 0; ni < 4; ++ni) bb[ni] = bc[bn * 256 + wn * 64 + ni * 16 + l15];
  const int u = bn * 64 + wn * 16 + l15;
  float wo[5];
#pragma unroll
  for (int o = 0; o < 5; ++o) wo[o] = W_out[o * HID + u];

  f16* cbase = c_ws + (((size_t)(bm * 16 + bn) * 8 + w) * 64 + lane) * 32;
  half8 cv[4];
  if (mode != 0) {
#pragma unroll
    for (int q = 0; q < 4; ++q) cv[q] = *(const half8*)(cbase + q * 8);
  }

#pragma unroll
  for (int mi = 0; mi < 8; ++mi) {
#pragma unroll
    for (int r = 0; r < 4; ++r) {
      const int row = bm * 256 + wm * 128 + mi * 16 + quad * 4 + r;
      const int ci = mi * 4 + r;
      float gi = acc[mi][0][r] + bb[0];
      float gf = acc[mi][1][r] + bb[1];
      float gg = acc[mi][2][r] + bb[2];
      float go = acc[mi][3][r] + bb[3];
      float co = (mode == 0) ? 0.f : (float)cv[ci >> 3][ci & 7];
      float cn = sigm(gf) * co + sigm(gi) * tanh_f(gg);
      cv[ci >> 3][ci & 7] = (f16)cn;
      float h = sigm(go) * tanh_f(cn);
      // h col = u ; frag index kh = u>>5 = slice ; A-frag layout for next step
      Xn[(((size_t)(row >> 4) * NKH + slice) * 64 + (quad * 4 + r) +
          16 * ((wn & 1) * 2 + (l15 >> 3))) * 8 + (l15 & 7)] = (f16)h;
      float pa[5];
#pragma unroll
      for (int o = 0; o < 5; ++o) pa[o] = h * wo[o];
#pragma unroll
      for (int o = 0; o < 5; ++o) {
        pa[o] += __shfl_xor(pa[o], 1, 64);
        pa[o] += __shfl_xor(pa[o], 2, 64);
        pa[o] += __shfl_xor(pa[o], 4, 64);
        pa[o] += __shfl_xor(pa[o], 8, 64);
      }
      if (l15 == 0) {
#pragma unroll
        for (int o = 0; o < 5; ++o) atomicAdd(out_t + (size_t)row * 5 + o, pa[o]);
      }
    }
  }
#pragma unroll
  for (int q = 0; q < 4; ++q) *(half8*)(cbase + q * 8) = cv[q];
}

// ---------------------------------------------------------------------------
extern "C" void kernel_launch(void* const* d_in, const int* in_sizes, int n_in,
                              void* d_out, int out_size, void* d_ws, size_t ws_size,
                              hipStream_t stream) {
  const float* observed = (const float*)d_in[0];
  const float* W_emb = (const float*)d_in[1];
  const float* b_emb = (const float*)d_in[2];
  const float* W_ih = (const float*)d_in[3];
  const float* b_ih = (const float*)d_in[4];
  const float* W_hh = (const float*)d_in[5];
  const float* b_hh = (const float*)d_in[6];
  const float* W_out = (const float*)d_in[7];
  const float* b_out = (const float*)d_in[8];
  float* out = (float*)d_out;

  uint8_t* ws = (uint8_t*)d_ws;
  const size_t WSW_BYTES = (size_t)32 * WSL * sizeof(f16);           // 8,912,896
  const size_t XH_BYTES = (size_t)256 * NKH * 64 * 8 * sizeof(f16);  // 8 MiB
  f16* Wsw = (f16*)ws;
  float* bc = (float*)(ws + WSW_BYTES);
  f16* X0 = (f16*)(ws + WSW_BYTES + 16384);
  f16* X1 = (f16*)(ws + WSW_BYTES + 16384 + XH_BYTES);
  f16* c_ws = (f16*)(ws + WSW_BYTES + 16384 + 2 * XH_BYTES);

  pack_kernel<<<(32 * WSL) / 256, 256, 0, stream>>>(W_ih, b_ih, W_hh, b_hh, Wsw, bc);
  init_out_kernel<<<(NSTEP * BATCH * 5) / 1024, 1024, 0, stream>>>(b_out, out);

  for (int t = 0; t < NSTEP; ++t) {
    f16* Xc = (t & 1) ? X1 : X0;  // h(t) written here
    f16* Xq = (t & 1) ? X0 : X1;  // h(t-1)
    const int mode = (t == 0) ? 0 : (t < NOBS ? 1 : 2);
    gemm_cell_kernel<<<256, 512, 0, stream>>>(
        Xq, Wsw, bc, c_ws, Xc, out + (size_t)t * BATCH * 5, W_out,
        observed + (size_t)t * BATCH * 2, out + (size_t)(t - 1) * BATCH * 5,
        mode, W_emb, b_emb);
  }
}

// Round 2
// 1134.469 us; speedup vs baseline: 3.1879x; 3.1879x over previous
//
#include <hip/hip_runtime.h>
#include <stdint.h>
#include <stddef.h>

#define BATCH 4096
#define HID   1024
#define EMB   64
#define NKH   32      // h K-tiles of 32
#define NSTEP 19
#define NOBS  8
#define WSL   139264  // halfs per 128-pcol slice of Wsw: 34*8*512

typedef _Float16 f16;
typedef _Float16 half8 __attribute__((ext_vector_type(8)));
typedef float    float4v __attribute__((ext_vector_type(4)));

__device__ __forceinline__ float sigm(float x) { return 1.f / (1.f + __expf(-x)); }
__device__ __forceinline__ float tanh_f(float x) { return 1.f - 2.f / (__expf(2.f * x) + 1.f); }

typedef const __attribute__((address_space(1))) unsigned int gau32;
typedef __attribute__((address_space(3))) unsigned int lau32;

__device__ __forceinline__ void gload16(const void* src, void* lds) {
  // global->LDS direct copy, 16 B/lane; LDS dest is wave-uniform base + lane*16
  __builtin_amdgcn_global_load_lds((gau32*)src, (lau32*)lds, 16, 0, 0);
}

// ---------------------------------------------------------------------------
// Pack W_ih|W_hh -> fragment-major fp16 Wsw[slice][kt][ni][lane][8].
// pcol mapping (gates within a wave's 4 ni tiles):
//   p = bn*256 + wn*64 + g*16 + v ; unit u = bn*64 + wn*16 + v ; orig = g*HID+u
//   i.e. g = (p>>4)&3, u = (p>>8)*64 + ((p>>6)&3)*16 + (p&15)
// k = kt*32 + (lane>>4)*8 + e ; kt 0,1 = emb (W_ih), kt 2..33 = h (W_hh).
// ---------------------------------------------------------------------------
__global__ void pack_kernel(const float* __restrict__ W_ih, const float* __restrict__ b_ih,
                            const float* __restrict__ W_hh, const float* __restrict__ b_hh,
                            f16* __restrict__ Wsw, float* __restrict__ bc) {
  int gid = blockIdx.x * blockDim.x + threadIdx.x;  // 32 * WSL
  int tt = gid / WSL;
  int rem = gid - tt * WSL;
  int kt = rem >> 12;
  int ni = (rem >> 9) & 7;
  int lane = (rem >> 3) & 63;
  int e = rem & 7;
  int p = tt * 128 + ni * 16 + (lane & 15);
  int g = (p >> 4) & 3;
  int u = (p >> 8) * 64 + ((p >> 6) & 3) * 16 + (p & 15);
  int orig = g * HID + u;
  int k = kt * 32 + ((lane >> 4) << 3) + e;
  float val = (k < EMB) ? W_ih[orig * EMB + k] : W_hh[orig * HID + (k - EMB)];
  Wsw[gid] = (f16)val;
  if (k == 0) bc[p] = b_ih[orig] + b_hh[orig];
}

// ---------------------------------------------------------------------------
// 256x256-tile fused gates-GEMM + LSTM cell + out-proj partials (no atomics).
// 8 waves (2M x 4N), BK=64, LDS double-buffered via global_load_lds,
// one __syncthreads per K-step, staging issued a full K-step ahead.
// Epilogue: lane-local cell, wn-reduction of out-proj partials through LDS,
// po_ws[16 bn slices][BATCH][5].
// ---------------------------------------------------------------------------
__global__ __launch_bounds__(512, 2)
void gemm_cell_kernel(const f16* __restrict__ Xp, const f16* __restrict__ Wsw,
                      const float* __restrict__ bc,
                      f16* __restrict__ c_ws, f16* __restrict__ Xn,
                      float* __restrict__ po_ws, const float* __restrict__ W_out,
                      const float* __restrict__ obs_t, const float* __restrict__ outprev,
                      int mode, const float* __restrict__ W_emb,
                      const float* __restrict__ b_emb) {
  __shared__ f16 smem[65536];  // 128 KiB: 2 bufs x (A 32KB + B 32KB)

  const int tid = threadIdx.x;
  const int lane = tid & 63;
  const int w = tid >> 6;
  const int l15 = lane & 15;
  const int quad = lane >> 4;
  const int wm = w >> 2, wn = w & 3;
  const int sh = wn >> 1, nq = wn & 1;

  // XCD swizzle: XCD x gets bn pair {2x,2x+1} (its B slices stay L2-resident)
  const int id = blockIdx.x;
  const int x = id & 7, rr0 = id >> 3;
  const int bn = x * 2 + (rr0 & 1);
  const int bm = rr0 >> 1;
  const int slice = bn * 2 + sh;  // 128-col slice this wave reads B from

  float4v acc[8][4];
#pragma unroll
  for (int mi = 0; mi < 8; ++mi)
#pragma unroll
    for (int ni = 0; ni < 4; ++ni) acc[mi][ni] = (float4v){0.f, 0.f, 0.f, 0.f};

  // stage K-step sp (1..16) into LDS buf (sp&1); 8 gloads per wave
  auto stage = [&](int sp) {
    const int p2 = sp & 1;
    const int khg = 2 * (sp - 1);
#pragma unroll
    for (int i = 0; i < 4; ++i) {  // A: this wave covers 4 of 32 chunks
      const int c = wn * 4 + i;
      const int rtl = wm * 8 + (c >> 1), khl = c & 1;
      const f16* src = Xp + ((size_t)(bm * 16 + rtl) * NKH + (khg + khl)) * 512 + lane * 8;
      f16* dst = smem + p2 * 32768 + (rtl * 2 + khl) * 512;
      gload16(src, dst);
    }
#pragma unroll
    for (int i = 0; i < 4; ++i) {  // B: 4 of 32 chunks (own slice half)
      const int c = (wm * 2 + nq) * 4 + i;
      const int nisl = c >> 1, khl = c & 1;
      const f16* src = Wsw + (size_t)slice * WSL + (2 + khg + khl) * 4096 + nisl * 512 + lane * 8;
      f16* dst = smem + p2 * 32768 + 16384 + ((sh * 8 + nisl) * 2 + khl) * 512;
      gload16(src, dst);
    }
  };

  if (mode != 0) stage(1);  // prologue staging flies under the emb phase

  // ---- emb phase (K 0..63), A computed in-register, B direct from global ----
  {
    float d0[8], d1[8];
#pragma unroll
    for (int mi = 0; mi < 8; ++mi) {
      const int row = (bm * 16 + wm * 8 + mi) * 16 + l15;
      if (mode <= 1) {
        const float* o = obs_t + (size_t)row * 2;
        d0[mi] = o[BATCH * 2] - o[0];
        d1[mi] = o[BATCH * 2 + 1] - o[1];
      } else {
        d0[mi] = outprev[(size_t)row * 5 + 0];
        d1[mi] = outprev[(size_t)row * 5 + 1];
      }
    }
#pragma unroll
    for (int kt = 0; kt < 2; ++kt) {
      float w0[8], w1[8], be[8];
#pragma unroll
      for (int e = 0; e < 8; ++e) {
        const int j = kt * 32 + quad * 8 + e;
        w0[e] = W_emb[2 * j];
        w1[e] = W_emb[2 * j + 1];
        be[e] = b_emb[j];
      }
      half8 bfe[4];
#pragma unroll
      for (int ni = 0; ni < 4; ++ni)
        bfe[ni] = *(const half8*)(Wsw + (size_t)slice * WSL + kt * 4096 + (nq * 4 + ni) * 512 + lane * 8);
#pragma unroll
      for (int mi = 0; mi < 8; ++mi) {
        half8 ae;
#pragma unroll
        for (int e = 0; e < 8; ++e)
          ae[e] = (f16)fmaxf(d0[mi] * w0[e] + d1[mi] * w1[e] + be[e], 0.f);
#pragma unroll
        for (int ni = 0; ni < 4; ++ni)
          acc[mi][ni] = __builtin_amdgcn_mfma_f32_16x16x32_f16(ae, bfe[ni], acc[mi][ni], 0, 0, 0);
      }
    }
  }

  // ---- h phase: 16 K-steps of 64, LDS double-buffered, khl-split compute ----
  if (mode != 0) {
    for (int s = 1; s <= 16; ++s) {
      __syncthreads();            // drains staging for s (issued one K-step ago)
      if (s < 16) stage(s + 1);   // in flight across this whole K-step

      const f16* base = smem + (s & 1) * 32768;
#pragma unroll
      for (int khl = 0; khl < 2; ++khl) {
        half8 a[8], bq[4];
#pragma unroll
        for (int mi = 0; mi < 8; ++mi)
          a[mi] = *(const half8*)(base + ((wm * 8 + mi) * 2 + khl) * 512 + lane * 8);
#pragma unroll
        for (int ni = 0; ni < 4; ++ni)
          bq[ni] = *(const half8*)(base + 16384 + ((sh * 8 + nq * 4 + ni) * 2 + khl) * 512 + lane * 8);
        __builtin_amdgcn_s_setprio(1);
#pragma unroll
        for (int mi = 0; mi < 8; ++mi)
#pragma unroll
          for (int ni = 0; ni < 4; ++ni)
            acc[mi][ni] =
                __builtin_amdgcn_mfma_f32_16x16x32_f16(a[mi], bq[ni], acc[mi][ni], 0, 0, 0);
        __builtin_amdgcn_s_setprio(0);
      }
    }
  }

  // ---- epilogue: lane-local LSTM cell + h write + wn-reduced partials ----
  float bb[4];
#pragma unroll
  for (int ni = 0; ni < 4; ++ni) bb[ni] = bc[bn * 256 + wn * 64 + ni * 16 + l15];
  const int u = bn * 64 + wn * 16 + l15;
  float wo[5];
#pragma unroll
  for (int o = 0; o < 5; ++o) wo[o] = W_out[o * HID + u];

  f16* cbase = c_ws + (((size_t)(bm * 16 + bn) * 8 + w) * 64 + lane) * 32;
  half8 cv[4];
  if (mode != 0) {
#pragma unroll
    for (int q = 0; q < 4; ++q) cv[q] = *(const half8*)(cbase + q * 8);
  }

  __syncthreads();                 // staged LDS no longer needed; reuse as pol
  float* pol = (float*)smem;       // [256 rows][4 wn][5]

#pragma unroll
  for (int mi = 0; mi < 8; ++mi) {
#pragma unroll
    for (int r = 0; r < 4; ++r) {
      const int rl = wm * 128 + mi * 16 + quad * 4 + r;  // row within block
      const int row = bm * 256 + rl;
      const int ci = mi * 4 + r;
      float gi = acc[mi][0][r] + bb[0];
      float gf = acc[mi][1][r] + bb[1];
      float gg = acc[mi][2][r] + bb[2];
      float go = acc[mi][3][r] + bb[3];
      float co = (mode == 0) ? 0.f : (float)cv[ci >> 3][ci & 7];
      float cn = sigm(gf) * co + sigm(gi) * tanh_f(gg);
      cv[ci >> 3][ci & 7] = (f16)cn;
      float h = sigm(go) * tanh_f(cn);
      // h col = u ; frag index kh = u>>5 = slice ; A-frag layout for next step
      Xn[(((size_t)(row >> 4) * NKH + slice) * 64 + (quad * 4 + r) +
          16 * ((wn & 1) * 2 + (l15 >> 3))) * 8 + (l15 & 7)] = (f16)h;
      float pa[5];
#pragma unroll
      for (int o = 0; o < 5; ++o) pa[o] = h * wo[o];
#pragma unroll
      for (int o = 0; o < 5; ++o) {
        pa[o] += __shfl_xor(pa[o], 1, 64);
        pa[o] += __shfl_xor(pa[o], 2, 64);
        pa[o] += __shfl_xor(pa[o], 4, 64);
        pa[o] += __shfl_xor(pa[o], 8, 64);
      }
      if (l15 == 0) {
#pragma unroll
        for (int o = 0; o < 5; ++o) pol[(rl * 4 + wn) * 5 + o] = pa[o];
      }
    }
  }
#pragma unroll
  for (int q = 0; q < 4; ++q) *(half8*)(cbase + q * 8) = cv[q];

  __syncthreads();
  for (int idx = tid; idx < 1280; idx += 512) {
    const int rl = idx / 5, o = idx - rl * 5;
    float s = 0.f;
#pragma unroll
    for (int j = 0; j < 4; ++j) s += pol[(rl * 4 + j) * 5 + o];
    po_ws[((size_t)bn * BATCH + bm * 256 + rl) * 5 + o] = s;
  }
}

// ---------------------------------------------------------------------------
// Reduce out-proj partials over 16 bn slices, add bias, write out.
// 128 blocks x 256 thr, 32 rows per block.
// ---------------------------------------------------------------------------
__global__ __launch_bounds__(256)
void reduce_kernel(const float* __restrict__ po_ws, const float* __restrict__ b_out,
                   float* __restrict__ out_t) {
  const int tid = threadIdx.x;
  const int r0 = blockIdx.x * 32;
  if (tid < 160) {
    const int rowl = tid / 5, o = tid - rowl * 5;
    const int row = r0 + rowl;
    float s = 0.f;
#pragma unroll
    for (int g = 0; g < 16; ++g) s += po_ws[((size_t)g * BATCH + row) * 5 + o];
    out_t[(size_t)row * 5 + o] = s + b_out[o];
  }
}

// ---------------------------------------------------------------------------
extern "C" void kernel_launch(void* const* d_in, const int* in_sizes, int n_in,
                              void* d_out, int out_size, void* d_ws, size_t ws_size,
                              hipStream_t stream) {
  const float* observed = (const float*)d_in[0];
  const float* W_emb = (const float*)d_in[1];
  const float* b_emb = (const float*)d_in[2];
  const float* W_ih = (const float*)d_in[3];
  const float* b_ih = (const float*)d_in[4];
  const float* W_hh = (const float*)d_in[5];
  const float* b_hh = (const float*)d_in[6];
  const float* W_out = (const float*)d_in[7];
  const float* b_out = (const float*)d_in[8];
  float* out = (float*)d_out;

  uint8_t* ws = (uint8_t*)d_ws;
  const size_t WSW_BYTES = (size_t)32 * WSL * sizeof(f16);           // 8,912,896
  const size_t XH_BYTES = (size_t)256 * NKH * 64 * 8 * sizeof(f16);  // 8 MiB
  f16* Wsw = (f16*)ws;
  float* bc = (float*)(ws + WSW_BYTES);
  f16* X0 = (f16*)(ws + WSW_BYTES + 16384);
  f16* X1 = (f16*)(ws + WSW_BYTES + 16384 + XH_BYTES);
  f16* c_ws = (f16*)(ws + WSW_BYTES + 16384 + 2 * XH_BYTES);
  float* po_ws = (float*)(ws + WSW_BYTES + 16384 + 2 * XH_BYTES + (size_t)BATCH * HID * 2);

  pack_kernel<<<(32 * WSL) / 256, 256, 0, stream>>>(W_ih, b_ih, W_hh, b_hh, Wsw, bc);

  for (int t = 0; t < NSTEP; ++t) {
    f16* Xc = (t & 1) ? X1 : X0;  // h(t) written here
    f16* Xq = (t & 1) ? X0 : X1;  // h(t-1)
    const int mode = (t == 0) ? 0 : (t < NOBS ? 1 : 2);
    gemm_cell_kernel<<<256, 512, 0, stream>>>(
        Xq, Wsw, bc, c_ws, Xc, po_ws, W_out,
        observed + (size_t)t * BATCH * 2, out + (size_t)(t - 1) * BATCH * 5,
        mode, W_emb, b_emb);
    reduce_kernel<<<BATCH / 32, 256, 0, stream>>>(po_ws, b_out, out + (size_t)t * BATCH * 5);
  }
}